// Round 1
// baseline (7997.720 us; speedup 1.0000x reference)
//
#include <hip/hip_runtime.h>
#include <math.h>

// Model constants (from reference)
constexpr int CL   = 2;
constexpr int CNH  = 12;
constexpr int CNKV = 2;
constexpr int CDH  = 128;
constexpr int CH   = 1536;
constexpr int CF   = 8960;
constexpr int CB   = 2;
constexpr int CS   = 1024;
constexpr int CQD  = CNH * CDH;    // 1536
constexpr int CKVD = CNKV * CDH;   // 256
constexpr int CROWS = CB * CS;     // 2048
constexpr int CGRP = CNH / CNKV;   // 6
constexpr float CEPS = 1e-6f;

__device__ inline float waveSum(float v) {
#pragma unroll
    for (int off = 32; off > 0; off >>= 1) v += __shfl_down(v, off, 64);
    return v;
}
__device__ inline float waveMax(float v) {
#pragma unroll
    for (int off = 32; off > 0; off >>= 1) v = fmaxf(v, __shfl_down(v, off, 64));
    return v;
}

// ---------------- embedding lookup ----------------
__global__ __launch_bounds__(256) void embed_kernel(const int* __restrict__ ids,
                                                    const float* __restrict__ emb,
                                                    float* __restrict__ x) {
    int row = blockIdx.x;
    int id = ids[row];
    const float* src = emb + (size_t)id * CH;
    float* dst = x + (size_t)row * CH;
    for (int j = threadIdx.x; j < CH; j += 256) dst[j] = src[j];
}

// ---------------- RMSNorm (one block per row, H=1536) ----------------
__global__ __launch_bounds__(256) void rmsnorm_kernel(const float* __restrict__ x,
                                                      const float* __restrict__ w,
                                                      float* __restrict__ out) {
    int row = blockIdx.x;
    const float* xr = x + (size_t)row * CH;
    float* orow = out + (size_t)row * CH;
    float vals[6];
    float local = 0.f;
#pragma unroll
    for (int i = 0; i < 6; i++) {
        float v = xr[threadIdx.x + i * 256];
        vals[i] = v;
        local += v * v;
    }
    local = waveSum(local);
    __shared__ float part[4];
    __shared__ float sscale;
    int wid = threadIdx.x >> 6, lane = threadIdx.x & 63;
    if (lane == 0) part[wid] = local;
    __syncthreads();
    if (threadIdx.x == 0) {
        float s = part[0] + part[1] + part[2] + part[3];
        sscale = rsqrtf(s / (float)CH + CEPS);
    }
    __syncthreads();
    float sc = sscale;
#pragma unroll
    for (int i = 0; i < 6; i++) {
        int j = threadIdx.x + i * 256;
        orow[j] = vals[i] * sc * w[j];
    }
}

// ---------------- fp32 tiled GEMM: C[M,N] = A[M,K] @ B[K,N] (+bias) (+=residual) ----
// 64x64 tile, BK=16, 256 threads, 4x4 accum per thread.
__global__ __launch_bounds__(256) void gemm_kernel(const float* __restrict__ A,
                                                   const float* __restrict__ Bm,
                                                   const float* __restrict__ bias,
                                                   float* __restrict__ C,
                                                   int M, int N, int K, int residual) {
    __shared__ __align__(16) float As[16][68];  // [k][m], padded: conflict-free + 16B rows
    __shared__ __align__(16) float Bs[16][64];  // [k][n]
    int tid = threadIdx.x;
    int tx = tid & 15, ty = tid >> 4;
    int m0 = blockIdx.y * 64, n0 = blockIdx.x * 64;
    float acc[4][4] = {};

    // A-load mapping: t -> m = t>>2 (0..63), kq = t&3 ; one float4 each
    int am = tid >> 2, akq = tid & 3;
    // B-load mapping: t -> kk = t>>4 (0..15), nq = t&15 ; one float4 each
    int bk = tid >> 4, bnq = tid & 15;

    for (int k0 = 0; k0 < K; k0 += 16) {
        float4 av = *(const float4*)&A[(size_t)(m0 + am) * K + k0 + akq * 4];
        float4 bv = *(const float4*)&Bm[(size_t)(k0 + bk) * N + n0 + bnq * 4];
        As[akq * 4 + 0][am] = av.x;
        As[akq * 4 + 1][am] = av.y;
        As[akq * 4 + 2][am] = av.z;
        As[akq * 4 + 3][am] = av.w;
        *(float4*)&Bs[bk][bnq * 4] = bv;
        __syncthreads();
#pragma unroll
        for (int kk = 0; kk < 16; kk++) {
            float4 a4 = *(const float4*)&As[kk][ty * 4];
            float4 b4 = *(const float4*)&Bs[kk][tx * 4];
            float a[4] = {a4.x, a4.y, a4.z, a4.w};
            float b[4] = {b4.x, b4.y, b4.z, b4.w};
#pragma unroll
            for (int i = 0; i < 4; i++)
#pragma unroll
                for (int j = 0; j < 4; j++) acc[i][j] += a[i] * b[j];
        }
        __syncthreads();
    }
#pragma unroll
    for (int i = 0; i < 4; i++) {
        int m = m0 + ty * 4 + i;
#pragma unroll
        for (int j = 0; j < 4; j++) {
            int n = n0 + tx * 4 + j;
            float v = acc[i][j];
            if (bias) v += bias[n];
            if (residual) C[(size_t)m * N + n] += v;
            else C[(size_t)m * N + n] = v;
        }
    }
}

// ---------------- fused gate/up GLU GEMM: C = silu(A@Bg) * (A@Bu) ----------------
__global__ __launch_bounds__(256) void glu_kernel(const float* __restrict__ A,
                                                  const float* __restrict__ Bg,
                                                  const float* __restrict__ Bu,
                                                  float* __restrict__ C,
                                                  int M, int N, int K) {
    __shared__ __align__(16) float As[16][68];
    __shared__ __align__(16) float Bgs[16][64];
    __shared__ __align__(16) float Bus[16][64];
    int tid = threadIdx.x;
    int tx = tid & 15, ty = tid >> 4;
    int m0 = blockIdx.y * 64, n0 = blockIdx.x * 64;
    float accg[4][4] = {};
    float accu[4][4] = {};
    int am = tid >> 2, akq = tid & 3;
    int bk = tid >> 4, bnq = tid & 15;

    for (int k0 = 0; k0 < K; k0 += 16) {
        float4 av = *(const float4*)&A[(size_t)(m0 + am) * K + k0 + akq * 4];
        float4 gv = *(const float4*)&Bg[(size_t)(k0 + bk) * N + n0 + bnq * 4];
        float4 uv = *(const float4*)&Bu[(size_t)(k0 + bk) * N + n0 + bnq * 4];
        As[akq * 4 + 0][am] = av.x;
        As[akq * 4 + 1][am] = av.y;
        As[akq * 4 + 2][am] = av.z;
        As[akq * 4 + 3][am] = av.w;
        *(float4*)&Bgs[bk][bnq * 4] = gv;
        *(float4*)&Bus[bk][bnq * 4] = uv;
        __syncthreads();
#pragma unroll
        for (int kk = 0; kk < 16; kk++) {
            float4 a4 = *(const float4*)&As[kk][ty * 4];
            float4 g4 = *(const float4*)&Bgs[kk][tx * 4];
            float4 u4 = *(const float4*)&Bus[kk][tx * 4];
            float a[4] = {a4.x, a4.y, a4.z, a4.w};
            float g[4] = {g4.x, g4.y, g4.z, g4.w};
            float u[4] = {u4.x, u4.y, u4.z, u4.w};
#pragma unroll
            for (int i = 0; i < 4; i++)
#pragma unroll
                for (int j = 0; j < 4; j++) {
                    accg[i][j] += a[i] * g[j];
                    accu[i][j] += a[i] * u[j];
                }
        }
        __syncthreads();
    }
#pragma unroll
    for (int i = 0; i < 4; i++) {
        int m = m0 + ty * 4 + i;
#pragma unroll
        for (int j = 0; j < 4; j++) {
            int n = n0 + tx * 4 + j;
            float g = accg[i][j];
            float u = accu[i][j];
            float s = g / (1.0f + __expf(-g));
            C[(size_t)m * N + n] = s * u;
        }
    }
}

// ---------------- RoPE in place on q (NH heads) and k (NKV heads) ----------------
// grid: (CROWS, NH+NKV), block 128
__global__ __launch_bounds__(128) void rope_kernel(float* __restrict__ q,
                                                   float* __restrict__ k) {
    int row = blockIdx.x;
    int hh = blockIdx.y;
    int s = row % CS;
    int t = threadIdx.x;
    float* p;
    if (hh < CNH) p = q + ((size_t)row * CNH + hh) * CDH;
    else p = k + ((size_t)row * CNKV + (hh - CNH)) * CDH;
    int jf = t & 63;
    // inv = theta^(-jf/64), theta = 1e6
    float inv = __expf(-(float)jf * (13.815510557964274f / 64.0f));
    float ang = (float)s * inv;
    float c = cosf(ang), si = sinf(ang);
    float x0 = p[t];
    float xo = p[t ^ 64];
    float rot = (t < 64) ? -xo : xo;
    __syncthreads();
    p[t] = x0 * c + rot * si;
}

// ---------------- attention: one block (128 thr) per (b, head, q-row) ----------------
__global__ __launch_bounds__(128) void attn_kernel(const float* __restrict__ q,
                                                   const float* __restrict__ k,
                                                   const float* __restrict__ v,
                                                   const int* __restrict__ amask,
                                                   float* __restrict__ o) {
    int qi = blockIdx.x;
    int h = blockIdx.y;
    int b = blockIdx.z;
    int t = threadIdx.x;
    int kvh = h / CGRP;
    __shared__ __align__(16) float qs[CDH];
    __shared__ float sc[CS];
    __shared__ float wred[2][2];
    const float scale = 0.08838834764831845f;  // 1/sqrt(128)

    qs[t] = q[(((size_t)(b * CS + qi)) * CNH + h) * CDH + t];
    __syncthreads();

    float lmax = -1e30f;
    const float4* q4 = (const float4*)qs;
    for (int kk = t; kk <= qi; kk += 128) {
        const float* kr = k + (((size_t)(b * CS + kk)) * CNKV + kvh) * CDH;
        const float4* k4 = (const float4*)kr;
        float dot = 0.f;
#pragma unroll 8
        for (int d = 0; d < CDH / 4; d++) {
            float4 kd = k4[d];
            float4 qd = q4[d];
            dot += qd.x * kd.x + qd.y * kd.y + qd.z * kd.z + qd.w * kd.w;
        }
        dot *= scale;
        if (amask[b * CS + kk] == 0) dot = -1e30f;
        sc[kk] = dot;
        lmax = fmaxf(lmax, dot);
    }
    lmax = waveMax(lmax);
    if ((t & 63) == 0) wred[0][t >> 6] = lmax;
    __syncthreads();
    float mx = fmaxf(wred[0][0], wred[0][1]);

    float lsum = 0.f;
    for (int kk = t; kk <= qi; kk += 128) {
        float e = __expf(sc[kk] - mx);
        sc[kk] = e;
        lsum += e;
    }
    lsum = waveSum(lsum);
    if ((t & 63) == 0) wred[1][t >> 6] = lsum;
    __syncthreads();
    float invsum = 1.0f / (wred[1][0] + wred[1][1]);

    // PV: thread t == d
    const float* vp = v + ((size_t)b * CS * CNKV + kvh) * CDH + t;
    float acc = 0.f;
    int kk = 0;
    for (; kk + 3 <= qi; kk += 4) {
        acc += sc[kk] * vp[(size_t)kk * CKVD];
        acc += sc[kk + 1] * vp[(size_t)(kk + 1) * CKVD];
        acc += sc[kk + 2] * vp[(size_t)(kk + 2) * CKVD];
        acc += sc[kk + 3] * vp[(size_t)(kk + 3) * CKVD];
    }
    for (; kk <= qi; kk++) acc += sc[kk] * vp[(size_t)kk * CKVD];
    o[(((size_t)(b * CS + qi)) * CNH + h) * CDH + t] = acc * invsum;
}

// ---------------- last_hidden gather ----------------
__global__ __launch_bounds__(256) void last_hidden_kernel(const float* __restrict__ hidden,
                                                          const int* __restrict__ amask,
                                                          float* __restrict__ outlast) {
    int b = blockIdx.x;
    float local = 0.f;
    for (int s = threadIdx.x; s < CS; s += 256) local += (float)amask[b * CS + s];
    local = waveSum(local);
    __shared__ float part[4];
    __shared__ int ssl;
    int wid = threadIdx.x >> 6, lane = threadIdx.x & 63;
    if (lane == 0) part[wid] = local;
    __syncthreads();
    if (threadIdx.x == 0) {
        ssl = (int)(part[0] + part[1] + part[2] + part[3]) - 1;
    }
    __syncthreads();
    int sl = ssl;
    for (int j = threadIdx.x; j < CH; j += 256)
        outlast[(size_t)b * CH + j] = hidden[((size_t)b * CS + sl) * CH + j];
}

extern "C" void kernel_launch(void* const* d_in, const int* in_sizes, int n_in,
                              void* d_out, int out_size, void* d_ws, size_t ws_size,
                              hipStream_t stream) {
    const int* ids = (const int*)d_in[0];
    const int* amask = (const int*)d_in[1];
    const float* emb = (const float*)d_in[2];
    const float* wq = (const float*)d_in[3];
    const float* bq = (const float*)d_in[4];
    const float* wk = (const float*)d_in[5];
    const float* bk = (const float*)d_in[6];
    const float* wv = (const float*)d_in[7];
    const float* bv = (const float*)d_in[8];
    const float* wo = (const float*)d_in[9];
    const float* wg = (const float*)d_in[10];
    const float* wu = (const float*)d_in[11];
    const float* wd = (const float*)d_in[12];
    const float* ln1 = (const float*)d_in[13];
    const float* ln2 = (const float*)d_in[14];
    const float* lnf = (const float*)d_in[15];
    float* out = (float*)d_out;

    // workspace layout (floats)
    float* ws = (float*)d_ws;
    float* x = ws;                                    // CROWS*CH
    float* h = x + (size_t)CROWS * CH;                // CROWS*CH
    float* qb = h + (size_t)CROWS * CH;               // CROWS*CQD
    float* kb = qb + (size_t)CROWS * CQD;             // CROWS*CKVD
    float* vb = kb + (size_t)CROWS * CKVD;            // CROWS*CKVD
    float* ob = vb + (size_t)CROWS * CKVD;            // CROWS*CQD
    float* act = ob + (size_t)CROWS * CQD;            // CROWS*CF

    embed_kernel<<<CROWS, 256, 0, stream>>>(ids, emb, x);

    for (int i = 0; i < CL; i++) {
        rmsnorm_kernel<<<CROWS, 256, 0, stream>>>(x, ln1 + (size_t)i * CH, h);

        gemm_kernel<<<dim3(CQD / 64, CROWS / 64), 256, 0, stream>>>(
            h, wq + (size_t)i * CH * CQD, bq + (size_t)i * CQD, qb, CROWS, CQD, CH, 0);
        gemm_kernel<<<dim3(CKVD / 64, CROWS / 64), 256, 0, stream>>>(
            h, wk + (size_t)i * CH * CKVD, bk + (size_t)i * CKVD, kb, CROWS, CKVD, CH, 0);
        gemm_kernel<<<dim3(CKVD / 64, CROWS / 64), 256, 0, stream>>>(
            h, wv + (size_t)i * CH * CKVD, bv + (size_t)i * CKVD, vb, CROWS, CKVD, CH, 0);

        rope_kernel<<<dim3(CROWS, CNH + CNKV), 128, 0, stream>>>(qb, kb);

        attn_kernel<<<dim3(CS, CNH, CB), 128, 0, stream>>>(qb, kb, vb, amask, ob);

        gemm_kernel<<<dim3(CH / 64, CROWS / 64), 256, 0, stream>>>(
            ob, wo + (size_t)i * CQD * CH, nullptr, x, CROWS, CH, CQD, 1);

        rmsnorm_kernel<<<CROWS, 256, 0, stream>>>(x, ln2 + (size_t)i * CH, h);

        glu_kernel<<<dim3(CF / 64, CROWS / 64), 256, 0, stream>>>(
            h, wg + (size_t)i * CH * CF, wu + (size_t)i * CH * CF, act, CROWS, CF, CH);

        gemm_kernel<<<dim3(CH / 64, CROWS / 64), 256, 0, stream>>>(
            act, wd + (size_t)i * CF * CH, nullptr, x, CROWS, CH, CF, 1);
    }

    rmsnorm_kernel<<<CROWS, 256, 0, stream>>>(x, lnf, out);
    last_hidden_kernel<<<CB, 256, 0, stream>>>(out, amask, out + (size_t)CROWS * CH);
}

// Round 2
// 3287.184 us; speedup vs baseline: 2.4330x; 2.4330x over previous
//
#include <hip/hip_runtime.h>
#include <math.h>

typedef __bf16 bf16_t;
typedef __bf16 bf16x8 __attribute__((ext_vector_type(8)));
typedef float f32x4 __attribute__((ext_vector_type(4)));

constexpr int CL   = 2;
constexpr int CNH  = 12;
constexpr int CNKV = 2;
constexpr int CDH  = 128;
constexpr int CH   = 1536;
constexpr int CF   = 8960;
constexpr int CB   = 2;
constexpr int CS   = 1024;
constexpr int CQD  = CNH * CDH;          // 1536
constexpr int CKVD = CNKV * CDH;         // 256
constexpr int CROWS = CB * CS;           // 2048
constexpr int CGRP = CNH / CNKV;         // 6
constexpr int CQKV = CQD + 2 * CKVD;     // 2048 (q|k|v packed)
constexpr float CEPS = 1e-6f;

__device__ inline float waveSum(float v) {
#pragma unroll
    for (int off = 32; off > 0; off >>= 1) v += __shfl_down(v, off, 64);
    return v;
}
__device__ inline float waveMax(float v) {
#pragma unroll
    for (int off = 32; off > 0; off >>= 1) v = fmaxf(v, __shfl_down(v, off, 64));
    return v;
}

__device__ __forceinline__ void async16(const bf16_t* g, bf16_t* l) {
    __builtin_amdgcn_global_load_lds(
        (const __attribute__((address_space(1))) void*)g,
        (__attribute__((address_space(3))) void*)l, 16, 0, 0);
}

// ---------------- embedding lookup ----------------
__global__ __launch_bounds__(256) void embed_kernel(const int* __restrict__ ids,
                                                    const float* __restrict__ emb,
                                                    float* __restrict__ x) {
    int row = blockIdx.x;
    int id = ids[row];
    const float* src = emb + (size_t)id * CH;
    float* dst = x + (size_t)row * CH;
    for (int j = threadIdx.x; j < CH; j += 256) dst[j] = src[j];
}

// ---------------- RMSNorm (one block per row, H=1536); out fp32 or bf16 ----------
__global__ __launch_bounds__(256) void rmsnorm_kernel(const float* __restrict__ x,
                                                      const float* __restrict__ w,
                                                      float* __restrict__ outf,
                                                      bf16_t* __restrict__ outb) {
    int row = blockIdx.x;
    const float* xr = x + (size_t)row * CH;
    float vals[6];
    float local = 0.f;
#pragma unroll
    for (int i = 0; i < 6; i++) {
        float v = xr[threadIdx.x + i * 256];
        vals[i] = v;
        local += v * v;
    }
    local = waveSum(local);
    __shared__ float part[4];
    __shared__ float sscale;
    int wid = threadIdx.x >> 6, lane = threadIdx.x & 63;
    if (lane == 0) part[wid] = local;
    __syncthreads();
    if (threadIdx.x == 0) {
        float s = part[0] + part[1] + part[2] + part[3];
        sscale = rsqrtf(s / (float)CH + CEPS);
    }
    __syncthreads();
    float sc = sscale;
#pragma unroll
    for (int i = 0; i < 6; i++) {
        int j = threadIdx.x + i * 256;
        float v = vals[i] * sc * w[j];
        if (outb) outb[(size_t)row * CH + j] = (bf16_t)v;
        else outf[(size_t)row * CH + j] = v;
    }
}

// ---------------- transpose + fp32->bf16: W[K,N] -> Wt[N,K] ----------------
// grid (N/32, K/32), block 256
__global__ __launch_bounds__(256) void convT_kernel(const float* __restrict__ W,
                                                    bf16_t* __restrict__ Wt,
                                                    int N, int K) {
    __shared__ float t[32][33];
    int n0 = blockIdx.x * 32, k0 = blockIdx.y * 32;
    int c = threadIdx.x & 31, rq = threadIdx.x >> 5;  // rq 0..7
#pragma unroll
    for (int i = 0; i < 4; i++) {
        int r = rq * 4 + i;
        t[r][c] = W[(size_t)(k0 + r) * N + n0 + c];
    }
    __syncthreads();
#pragma unroll
    for (int i = 0; i < 4; i++) {
        int r = rq * 4 + i;  // r = n offset now
        Wt[(size_t)(n0 + r) * K + k0 + c] = (bf16_t)t[c][r];
    }
}

// ---------------- pack qkv bias: [L][1536|256|256] -> [L][2048] ----------------
__global__ __launch_bounds__(256) void pack_bias_kernel(const float* __restrict__ bq,
                                                        const float* __restrict__ bk,
                                                        const float* __restrict__ bv,
                                                        float* __restrict__ dst) {
    int i = blockIdx.x * 256 + threadIdx.x;  // over CL*2048
    int l = i >> 11, c = i & 2047;
    float v;
    if (c < CQD) v = bq[l * CQD + c];
    else if (c < CQD + CKVD) v = bk[l * CKVD + c - CQD];
    else v = bv[l * CKVD + c - CQD - CKVD];
    dst[i] = v;
}

// ---------------- bf16 MFMA GEMM: C[M,N] = A[M,K] @ Bt[N,K]^T (+bias) ----------------
// 128x128 tile, BK=32, 256 threads (2x2 waves, each 64x64 = 4x4 mfma tiles)
// mode 0: Cf = acc + bias ; mode 1: Cf += acc
constexpr int BM = 128, BN = 128, BK = 32;

__global__ __launch_bounds__(256, 2) void gemm_bf16(const bf16_t* __restrict__ A,
                                                    const bf16_t* __restrict__ Bt,
                                                    const float* __restrict__ bias,
                                                    float* __restrict__ Cf,
                                                    int M, int N, int K, int mode) {
    __shared__ __align__(16) bf16_t As[BM * BK];
    __shared__ __align__(16) bf16_t Bs[BN * BK];
    int tid = threadIdx.x;
    int wave = tid >> 6, lane = tid & 63;
    int m0 = blockIdx.y * BM, n0 = blockIdx.x * BN;

    // staging mapping: round r covers rows r*64..r*64+63; this thread handles
    // row = r*64 + wave*16 + (lane>>2), k-offset (lane&3)*8, 16 bytes
    int srow = wave * 16 + (lane >> 2);
    int skof = (lane & 3) * 8;
    const bf16_t* Ag0 = A + (size_t)(m0 + srow) * K + skof;
    const bf16_t* Ag1 = A + (size_t)(m0 + 64 + srow) * K + skof;
    const bf16_t* Bg0 = Bt + (size_t)(n0 + srow) * K + skof;
    const bf16_t* Bg1 = Bt + (size_t)(n0 + 64 + srow) * K + skof;
    bf16_t* As0 = &As[(wave * 16) * BK];
    bf16_t* As1 = &As[(64 + wave * 16) * BK];
    bf16_t* Bs0 = &Bs[(wave * 16) * BK];
    bf16_t* Bs1 = &Bs[(64 + wave * 16) * BK];

    int wr = wave >> 1, wc = wave & 1;
    int fr = lane & 15, fq = lane >> 4;

    f32x4 acc[4][4];
#pragma unroll
    for (int i = 0; i < 4; i++)
#pragma unroll
        for (int j = 0; j < 4; j++) acc[i][j] = {0.f, 0.f, 0.f, 0.f};

    for (int k0 = 0; k0 < K; k0 += BK) {
        async16(Ag0 + k0, As0);
        async16(Ag1 + k0, As1);
        async16(Bg0 + k0, Bs0);
        async16(Bg1 + k0, Bs1);
        __syncthreads();
        bf16x8 af[4], bfv[4];
#pragma unroll
        for (int i = 0; i < 4; i++)
            af[i] = *(const bf16x8*)&As[(wr * 64 + i * 16 + fr) * BK + fq * 8];
#pragma unroll
        for (int j = 0; j < 4; j++)
            bfv[j] = *(const bf16x8*)&Bs[(wc * 64 + j * 16 + fr) * BK + fq * 8];
#pragma unroll
        for (int i = 0; i < 4; i++)
#pragma unroll
            for (int j = 0; j < 4; j++)
                acc[i][j] = __builtin_amdgcn_mfma_f32_16x16x32_bf16(af[i], bfv[j], acc[i][j], 0, 0, 0);
        __syncthreads();
    }

#pragma unroll
    for (int i = 0; i < 4; i++) {
        int mbase = m0 + wr * 64 + i * 16 + fq * 4;
#pragma unroll
        for (int j = 0; j < 4; j++) {
            int n = n0 + wc * 64 + j * 16 + fr;
            float bv = bias ? bias[n] : 0.f;
#pragma unroll
            for (int rr = 0; rr < 4; rr++) {
                size_t idx = (size_t)(mbase + rr) * N + n;
                float v = acc[i][j][rr] + bv;
                if (mode == 0) Cf[idx] = v;
                else Cf[idx] += v;
            }
        }
    }
}

// ---------------- fused GLU MFMA: out_bf16 = silu(A@Bg^T) * (A@Bu^T) ----------------
__global__ __launch_bounds__(256, 2) void glu_bf16(const bf16_t* __restrict__ A,
                                                   const bf16_t* __restrict__ Bg,
                                                   const bf16_t* __restrict__ Bu,
                                                   bf16_t* __restrict__ Cb,
                                                   int M, int N, int K) {
    __shared__ __align__(16) bf16_t As[BM * BK];
    __shared__ __align__(16) bf16_t Bgs[BN * BK];
    __shared__ __align__(16) bf16_t Bus[BN * BK];
    int tid = threadIdx.x;
    int wave = tid >> 6, lane = tid & 63;
    int m0 = blockIdx.y * BM, n0 = blockIdx.x * BN;

    int srow = wave * 16 + (lane >> 2);
    int skof = (lane & 3) * 8;
    const bf16_t* Ag0 = A + (size_t)(m0 + srow) * K + skof;
    const bf16_t* Ag1 = A + (size_t)(m0 + 64 + srow) * K + skof;
    const bf16_t* Gg0 = Bg + (size_t)(n0 + srow) * K + skof;
    const bf16_t* Gg1 = Bg + (size_t)(n0 + 64 + srow) * K + skof;
    const bf16_t* Ug0 = Bu + (size_t)(n0 + srow) * K + skof;
    const bf16_t* Ug1 = Bu + (size_t)(n0 + 64 + srow) * K + skof;
    bf16_t* As0 = &As[(wave * 16) * BK];
    bf16_t* As1 = &As[(64 + wave * 16) * BK];
    bf16_t* Gs0 = &Bgs[(wave * 16) * BK];
    bf16_t* Gs1 = &Bgs[(64 + wave * 16) * BK];
    bf16_t* Us0 = &Bus[(wave * 16) * BK];
    bf16_t* Us1 = &Bus[(64 + wave * 16) * BK];

    int wr = wave >> 1, wc = wave & 1;
    int fr = lane & 15, fq = lane >> 4;

    f32x4 accg[4][4], accu[4][4];
#pragma unroll
    for (int i = 0; i < 4; i++)
#pragma unroll
        for (int j = 0; j < 4; j++) {
            accg[i][j] = {0.f, 0.f, 0.f, 0.f};
            accu[i][j] = {0.f, 0.f, 0.f, 0.f};
        }

    for (int k0 = 0; k0 < K; k0 += BK) {
        async16(Ag0 + k0, As0);
        async16(Ag1 + k0, As1);
        async16(Gg0 + k0, Gs0);
        async16(Gg1 + k0, Gs1);
        async16(Ug0 + k0, Us0);
        async16(Ug1 + k0, Us1);
        __syncthreads();
        bf16x8 af[4], gf[4], uf[4];
#pragma unroll
        for (int i = 0; i < 4; i++)
            af[i] = *(const bf16x8*)&As[(wr * 64 + i * 16 + fr) * BK + fq * 8];
#pragma unroll
        for (int j = 0; j < 4; j++) {
            gf[j] = *(const bf16x8*)&Bgs[(wc * 64 + j * 16 + fr) * BK + fq * 8];
            uf[j] = *(const bf16x8*)&Bus[(wc * 64 + j * 16 + fr) * BK + fq * 8];
        }
#pragma unroll
        for (int i = 0; i < 4; i++)
#pragma unroll
            for (int j = 0; j < 4; j++) {
                accg[i][j] = __builtin_amdgcn_mfma_f32_16x16x32_bf16(af[i], gf[j], accg[i][j], 0, 0, 0);
                accu[i][j] = __builtin_amdgcn_mfma_f32_16x16x32_bf16(af[i], uf[j], accu[i][j], 0, 0, 0);
            }
        __syncthreads();
    }

#pragma unroll
    for (int i = 0; i < 4; i++) {
        int mbase = m0 + wr * 64 + i * 16 + fq * 4;
#pragma unroll
        for (int j = 0; j < 4; j++) {
            int n = n0 + wc * 64 + j * 16 + fr;
#pragma unroll
            for (int rr = 0; rr < 4; rr++) {
                float g = accg[i][j][rr];
                float u = accu[i][j][rr];
                float s = g / (1.f + __expf(-g));
                Cb[(size_t)(mbase + rr) * N + n] = (bf16_t)(s * u);
            }
        }
    }
}

// ---------------- RoPE in place on packed qkv [M, 2048] ----------------
// grid: (CROWS, NH+NKV), block 128
__global__ __launch_bounds__(128) void rope_kernel(float* __restrict__ qkv) {
    int row = blockIdx.x;
    int hh = blockIdx.y;
    int s = row % CS;
    int t = threadIdx.x;
    float* p = qkv + (size_t)row * CQKV +
               (hh < CNH ? hh * CDH : CQD + (hh - CNH) * CDH);
    int jf = t & 63;
    float inv = __expf(-(float)jf * (13.815510557964274f / 64.0f));  // theta^-jf/64
    float ang = (float)s * inv;
    float c = cosf(ang), si = sinf(ang);
    float x0 = p[t];
    float xo = p[t ^ 64];
    float rot = (t < 64) ? -xo : xo;
    __syncthreads();
    p[t] = x0 * c + rot * si;
}

// ---------------- attention on packed qkv; writes bf16 output [M, 1536] ------------
__global__ __launch_bounds__(128) void attn_kernel(const float* __restrict__ qkv,
                                                   const int* __restrict__ amask,
                                                   bf16_t* __restrict__ o) {
    int qi = blockIdx.x;
    int h = blockIdx.y;
    int b = blockIdx.z;
    int t = threadIdx.x;
    int kvh = h / CGRP;
    __shared__ __align__(16) float qs[CDH];
    __shared__ float sc[CS];
    __shared__ float wred[2][2];
    const float scale = 0.08838834764831845f;  // 1/sqrt(128)

    qs[t] = qkv[(size_t)(b * CS + qi) * CQKV + h * CDH + t];
    __syncthreads();

    float lmax = -1e30f;
    const float4* q4 = (const float4*)qs;
    for (int kk = t; kk <= qi; kk += 128) {
        const float* kr = qkv + (size_t)(b * CS + kk) * CQKV + CQD + kvh * CDH;
        const float4* k4 = (const float4*)kr;
        float dot = 0.f;
#pragma unroll 8
        for (int d = 0; d < CDH / 4; d++) {
            float4 kd = k4[d];
            float4 qd = q4[d];
            dot += qd.x * kd.x + qd.y * kd.y + qd.z * kd.z + qd.w * kd.w;
        }
        dot *= scale;
        if (amask[b * CS + kk] == 0) dot = -1e30f;
        sc[kk] = dot;
        lmax = fmaxf(lmax, dot);
    }
    lmax = waveMax(lmax);
    if ((t & 63) == 0) wred[0][t >> 6] = lmax;
    __syncthreads();
    float mx = fmaxf(wred[0][0], wred[0][1]);

    float lsum = 0.f;
    for (int kk = t; kk <= qi; kk += 128) {
        float e = __expf(sc[kk] - mx);
        sc[kk] = e;
        lsum += e;
    }
    lsum = waveSum(lsum);
    if ((t & 63) == 0) wred[1][t >> 6] = lsum;
    __syncthreads();
    float invsum = 1.0f / (wred[1][0] + wred[1][1]);

    const float* vp = qkv + (size_t)(b * CS) * CQKV + CQD + CKVD + kvh * CDH + t;
    float acc = 0.f;
    int kk = 0;
    for (; kk + 3 <= qi; kk += 4) {
        acc += sc[kk] * vp[(size_t)kk * CQKV];
        acc += sc[kk + 1] * vp[(size_t)(kk + 1) * CQKV];
        acc += sc[kk + 2] * vp[(size_t)(kk + 2) * CQKV];
        acc += sc[kk + 3] * vp[(size_t)(kk + 3) * CQKV];
    }
    for (; kk <= qi; kk++) acc += sc[kk] * vp[(size_t)kk * CQKV];
    o[(size_t)(b * CS + qi) * CQD + h * CDH + t] = (bf16_t)(acc * invsum);
}

// ---------------- last_hidden gather ----------------
__global__ __launch_bounds__(256) void last_hidden_kernel(const float* __restrict__ hidden,
                                                          const int* __restrict__ amask,
                                                          float* __restrict__ outlast) {
    int b = blockIdx.x;
    float local = 0.f;
    for (int s = threadIdx.x; s < CS; s += 256) local += (float)amask[b * CS + s];
    local = waveSum(local);
    __shared__ float part[4];
    __shared__ int ssl;
    int wid = threadIdx.x >> 6, lane = threadIdx.x & 63;
    if (lane == 0) part[wid] = local;
    __syncthreads();
    if (threadIdx.x == 0) ssl = (int)(part[0] + part[1] + part[2] + part[3]) - 1;
    __syncthreads();
    int sl = ssl;
    for (int j = threadIdx.x; j < CH; j += 256)
        outlast[(size_t)b * CH + j] = hidden[((size_t)b * CS + sl) * CH + j];
}

extern "C" void kernel_launch(void* const* d_in, const int* in_sizes, int n_in,
                              void* d_out, int out_size, void* d_ws, size_t ws_size,
                              hipStream_t stream) {
    const int* ids = (const int*)d_in[0];
    const int* amask = (const int*)d_in[1];
    const float* emb = (const float*)d_in[2];
    const float* wq = (const float*)d_in[3];
    const float* bq = (const float*)d_in[4];
    const float* wk = (const float*)d_in[5];
    const float* bk = (const float*)d_in[6];
    const float* wv = (const float*)d_in[7];
    const float* bv = (const float*)d_in[8];
    const float* wo = (const float*)d_in[9];
    const float* wg = (const float*)d_in[10];
    const float* wu = (const float*)d_in[11];
    const float* wd = (const float*)d_in[12];
    const float* ln1 = (const float*)d_in[13];
    const float* ln2 = (const float*)d_in[14];
    const float* lnf = (const float*)d_in[15];
    float* out = (float*)d_out;

    // workspace layout (~127.4 MB)
    char* p = (char*)d_ws;
    float* x = (float*)p;      p += (size_t)CROWS * CH * 4;     // 12.6 MB
    float* qkv = (float*)p;    p += (size_t)CROWS * CQKV * 4;   // 16.8 MB
    bf16_t* hb = (bf16_t*)p;   p += (size_t)CROWS * CH * 2;     // 6.3 MB
    bf16_t* act = (bf16_t*)p;  p += (size_t)CROWS * CF * 2;     // 36.7 MB
    bf16_t* wbuf = (bf16_t*)p; p += (size_t)2 * CF * CH * 2;    // 55.1 MB
    float* biasq = (float*)p;  p += (size_t)CL * CQKV * 4;      // 16 KB

    embed_kernel<<<CROWS, 256, 0, stream>>>(ids, emb, x);
    pack_bias_kernel<<<CL * CQKV / 256, 256, 0, stream>>>(bq, bk, bv, biasq);

    for (int i = 0; i < CL; i++) {
        // ln1 -> hb (bf16)
        rmsnorm_kernel<<<CROWS, 256, 0, stream>>>(x, ln1 + (size_t)i * CH, nullptr, hb);

        // qkv fused GEMM: weights packed transposed into wbuf [2048][1536]
        convT_kernel<<<dim3(CQD / 32, CH / 32), 256, 0, stream>>>(
            wq + (size_t)i * CH * CQD, wbuf, CQD, CH);
        convT_kernel<<<dim3(CKVD / 32, CH / 32), 256, 0, stream>>>(
            wk + (size_t)i * CH * CKVD, wbuf + (size_t)CQD * CH, CKVD, CH);
        convT_kernel<<<dim3(CKVD / 32, CH / 32), 256, 0, stream>>>(
            wv + (size_t)i * CH * CKVD, wbuf + (size_t)(CQD + CKVD) * CH, CKVD, CH);
        gemm_bf16<<<dim3(CQKV / BN, CROWS / BM), 256, 0, stream>>>(
            hb, wbuf, biasq + (size_t)i * CQKV, qkv, CROWS, CQKV, CH, 0);

        rope_kernel<<<dim3(CROWS, CNH + CNKV), 128, 0, stream>>>(qkv);

        attn_kernel<<<dim3(CS, CNH, CB), 128, 0, stream>>>(qkv, amask, hb);

        // x += attn_out @ wo
        convT_kernel<<<dim3(CH / 32, CQD / 32), 256, 0, stream>>>(
            wo + (size_t)i * CQD * CH, wbuf, CH, CQD);
        gemm_bf16<<<dim3(CH / BN, CROWS / BM), 256, 0, stream>>>(
            hb, wbuf, nullptr, x, CROWS, CH, CQD, 1);

        // ln2 -> hb (bf16)
        rmsnorm_kernel<<<CROWS, 256, 0, stream>>>(x, ln2 + (size_t)i * CH, nullptr, hb);

        // fused GLU
        convT_kernel<<<dim3(CF / 32, CH / 32), 256, 0, stream>>>(
            wg + (size_t)i * CH * CF, wbuf, CF, CH);
        convT_kernel<<<dim3(CF / 32, CH / 32), 256, 0, stream>>>(
            wu + (size_t)i * CH * CF, wbuf + (size_t)CF * CH, CF, CH);
        glu_bf16<<<dim3(CF / BN, CROWS / BM), 256, 0, stream>>>(
            hb, wbuf, wbuf + (size_t)CF * CH, act, CROWS, CF, CH);

        // x += act @ wd
        convT_kernel<<<dim3(CH / 32, CF / 32), 256, 0, stream>>>(
            wd + (size_t)i * CF * CH, wbuf, CH, CF);
        gemm_bf16<<<dim3(CH / BN, CROWS / BM), 256, 0, stream>>>(
            act, wbuf, nullptr, x, CROWS, CH, CF, 1);
    }

    rmsnorm_kernel<<<CROWS, 256, 0, stream>>>(x, lnf, out, nullptr);
    last_hidden_kernel<<<CB, 256, 0, stream>>>(out, amask, out + (size_t)CROWS * CH);
}

// Round 4
// 1568.575 us; speedup vs baseline: 5.0987x; 2.0957x over previous
//
#include <hip/hip_runtime.h>
#include <math.h>

typedef __bf16 bf16_t;
typedef __bf16 bf16x8 __attribute__((ext_vector_type(8)));
typedef float f32x4 __attribute__((ext_vector_type(4)));

constexpr int CL   = 2;
constexpr int CNH  = 12;
constexpr int CNKV = 2;
constexpr int CDH  = 128;
constexpr int CH   = 1536;
constexpr int CF   = 8960;
constexpr int CB   = 2;
constexpr int CS   = 1024;
constexpr int CQD  = CNH * CDH;          // 1536
constexpr int CKVD = CNKV * CDH;         // 256
constexpr int CROWS = CB * CS;           // 2048
constexpr int CGRP = CNH / CNKV;         // 6
constexpr int CQKV = CQD + 2 * CKVD;     // 2048 (q|k|v packed)
constexpr float CEPS = 1e-6f;

__device__ inline float waveSum(float v) {
#pragma unroll
    for (int off = 32; off > 0; off >>= 1) v += __shfl_down(v, off, 64);
    return v;
}

__device__ __forceinline__ void async16(const bf16_t* g, bf16_t* l) {
    __builtin_amdgcn_global_load_lds(
        (const __attribute__((address_space(1))) void*)g,
        (__attribute__((address_space(3))) void*)l, 16, 0, 0);
}

// ---------------- embedding lookup ----------------
__global__ __launch_bounds__(256) void embed_kernel(const int* __restrict__ ids,
                                                    const float* __restrict__ emb,
                                                    float* __restrict__ x) {
    int row = blockIdx.x;
    int id = ids[row];
    const float* src = emb + (size_t)id * CH;
    float* dst = x + (size_t)row * CH;
    for (int j = threadIdx.x; j < CH; j += 256) dst[j] = src[j];
}

// ---------------- RMSNorm (one block per row, H=1536); out fp32 or bf16 ----------
__global__ __launch_bounds__(256) void rmsnorm_kernel(const float* __restrict__ x,
                                                      const float* __restrict__ w,
                                                      float* __restrict__ outf,
                                                      bf16_t* __restrict__ outb) {
    int row = blockIdx.x;
    const float* xr = x + (size_t)row * CH;
    float vals[6];
    float local = 0.f;
#pragma unroll
    for (int i = 0; i < 6; i++) {
        float v = xr[threadIdx.x + i * 256];
        vals[i] = v;
        local += v * v;
    }
    local = waveSum(local);
    __shared__ float part[4];
    __shared__ float sscale;
    int wid = threadIdx.x >> 6, lane = threadIdx.x & 63;
    if (lane == 0) part[wid] = local;
    __syncthreads();
    if (threadIdx.x == 0) {
        float s = part[0] + part[1] + part[2] + part[3];
        sscale = rsqrtf(s / (float)CH + CEPS);
    }
    __syncthreads();
    float sc = sscale;
#pragma unroll
    for (int i = 0; i < 6; i++) {
        int j = threadIdx.x + i * 256;
        float v = vals[i] * sc * w[j];
        if (outb) outb[(size_t)row * CH + j] = (bf16_t)v;
        else outf[(size_t)row * CH + j] = v;
    }
}

// ---------------- transpose + fp32->bf16: W[K,N] -> Wt[N,K] ----------------
__global__ __launch_bounds__(256) void convT_kernel(const float* __restrict__ W,
                                                    bf16_t* __restrict__ Wt,
                                                    int N, int K) {
    __shared__ float t[32][33];
    int n0 = blockIdx.x * 32, k0 = blockIdx.y * 32;
    int c = threadIdx.x & 31, rq = threadIdx.x >> 5;
#pragma unroll
    for (int i = 0; i < 4; i++) {
        int r = rq * 4 + i;
        t[r][c] = W[(size_t)(k0 + r) * N + n0 + c];
    }
    __syncthreads();
#pragma unroll
    for (int i = 0; i < 4; i++) {
        int r = rq * 4 + i;
        Wt[(size_t)(n0 + r) * K + k0 + c] = (bf16_t)t[c][r];
    }
}

// ---------------- pack qkv bias ----------------
__global__ __launch_bounds__(256) void pack_bias_kernel(const float* __restrict__ bq,
                                                        const float* __restrict__ bk,
                                                        const float* __restrict__ bv,
                                                        float* __restrict__ dst) {
    int i = blockIdx.x * 256 + threadIdx.x;
    int l = i >> 11, c = i & 2047;
    float v;
    if (c < CQD) v = bq[l * CQD + c];
    else if (c < CQD + CKVD) v = bk[l * CKVD + c - CQD];
    else v = bv[l * CKVD + c - CQD - CKVD];
    dst[i] = v;
}

// ---------------- bf16 MFMA GEMM: C[M,N] = A[M,K] @ Bt[N,K]^T (+bias) ----------------
constexpr int BM = 128, BN = 128, BK = 32;

__global__ __launch_bounds__(256, 2) void gemm_bf16(const bf16_t* __restrict__ A,
                                                    const bf16_t* __restrict__ Bt,
                                                    const float* __restrict__ bias,
                                                    float* __restrict__ Cf,
                                                    int M, int N, int K, int mode) {
    __shared__ __align__(16) bf16_t As[BM * BK];
    __shared__ __align__(16) bf16_t Bs[BN * BK];
    int tid = threadIdx.x;
    int wave = tid >> 6, lane = tid & 63;
    int m0 = blockIdx.y * BM, n0 = blockIdx.x * BN;

    int srow = wave * 16 + (lane >> 2);
    int skof = (lane & 3) * 8;
    const bf16_t* Ag0 = A + (size_t)(m0 + srow) * K + skof;
    const bf16_t* Ag1 = A + (size_t)(m0 + 64 + srow) * K + skof;
    const bf16_t* Bg0 = Bt + (size_t)(n0 + srow) * K + skof;
    const bf16_t* Bg1 = Bt + (size_t)(n0 + 64 + srow) * K + skof;
    bf16_t* As0 = &As[(wave * 16) * BK];
    bf16_t* As1 = &As[(64 + wave * 16) * BK];
    bf16_t* Bs0 = &Bs[(wave * 16) * BK];
    bf16_t* Bs1 = &Bs[(64 + wave * 16) * BK];

    int wr = wave >> 1, wc = wave & 1;
    int fr = lane & 15, fq = lane >> 4;

    f32x4 acc[4][4];
#pragma unroll
    for (int i = 0; i < 4; i++)
#pragma unroll
        for (int j = 0; j < 4; j++) acc[i][j] = {0.f, 0.f, 0.f, 0.f};

    for (int k0 = 0; k0 < K; k0 += BK) {
        async16(Ag0 + k0, As0);
        async16(Ag1 + k0, As1);
        async16(Bg0 + k0, Bs0);
        async16(Bg1 + k0, Bs1);
        __syncthreads();
        bf16x8 af[4], bfv[4];
#pragma unroll
        for (int i = 0; i < 4; i++)
            af[i] = *(const bf16x8*)&As[(wr * 64 + i * 16 + fr) * BK + fq * 8];
#pragma unroll
        for (int j = 0; j < 4; j++)
            bfv[j] = *(const bf16x8*)&Bs[(wc * 64 + j * 16 + fr) * BK + fq * 8];
#pragma unroll
        for (int i = 0; i < 4; i++)
#pragma unroll
            for (int j = 0; j < 4; j++)
                acc[i][j] = __builtin_amdgcn_mfma_f32_16x16x32_bf16(af[i], bfv[j], acc[i][j], 0, 0, 0);
        __syncthreads();
    }

#pragma unroll
    for (int i = 0; i < 4; i++) {
        int mbase = m0 + wr * 64 + i * 16 + fq * 4;
#pragma unroll
        for (int j = 0; j < 4; j++) {
            int n = n0 + wc * 64 + j * 16 + fr;
            float bv = bias ? bias[n] : 0.f;
#pragma unroll
            for (int rr = 0; rr < 4; rr++) {
                size_t idx = (size_t)(mbase + rr) * N + n;
                float v = acc[i][j][rr] + bv;
                if (mode == 0) Cf[idx] = v;
                else Cf[idx] += v;
            }
        }
    }
}

// ---------------- fused GLU MFMA: out_bf16 = silu(A@Bg^T) * (A@Bu^T) ----------------
__global__ __launch_bounds__(256, 2) void glu_bf16(const bf16_t* __restrict__ A,
                                                   const bf16_t* __restrict__ Bg,
                                                   const bf16_t* __restrict__ Bu,
                                                   bf16_t* __restrict__ Cb,
                                                   int M, int N, int K) {
    __shared__ __align__(16) bf16_t As[BM * BK];
    __shared__ __align__(16) bf16_t Bgs[BN * BK];
    __shared__ __align__(16) bf16_t Bus[BN * BK];
    int tid = threadIdx.x;
    int wave = tid >> 6, lane = tid & 63;
    int m0 = blockIdx.y * BM, n0 = blockIdx.x * BN;

    int srow = wave * 16 + (lane >> 2);
    int skof = (lane & 3) * 8;
    const bf16_t* Ag0 = A + (size_t)(m0 + srow) * K + skof;
    const bf16_t* Ag1 = A + (size_t)(m0 + 64 + srow) * K + skof;
    const bf16_t* Gg0 = Bg + (size_t)(n0 + srow) * K + skof;
    const bf16_t* Gg1 = Bg + (size_t)(n0 + 64 + srow) * K + skof;
    const bf16_t* Ug0 = Bu + (size_t)(n0 + srow) * K + skof;
    const bf16_t* Ug1 = Bu + (size_t)(n0 + 64 + srow) * K + skof;
    bf16_t* As0 = &As[(wave * 16) * BK];
    bf16_t* As1 = &As[(64 + wave * 16) * BK];
    bf16_t* Gs0 = &Bgs[(wave * 16) * BK];
    bf16_t* Gs1 = &Bgs[(64 + wave * 16) * BK];
    bf16_t* Us0 = &Bus[(wave * 16) * BK];
    bf16_t* Us1 = &Bus[(64 + wave * 16) * BK];

    int wr = wave >> 1, wc = wave & 1;
    int fr = lane & 15, fq = lane >> 4;

    f32x4 accg[4][4], accu[4][4];
#pragma unroll
    for (int i = 0; i < 4; i++)
#pragma unroll
        for (int j = 0; j < 4; j++) {
            accg[i][j] = {0.f, 0.f, 0.f, 0.f};
            accu[i][j] = {0.f, 0.f, 0.f, 0.f};
        }

    for (int k0 = 0; k0 < K; k0 += BK) {
        async16(Ag0 + k0, As0);
        async16(Ag1 + k0, As1);
        async16(Gg0 + k0, Gs0);
        async16(Gg1 + k0, Gs1);
        async16(Ug0 + k0, Us0);
        async16(Ug1 + k0, Us1);
        __syncthreads();
        bf16x8 af[4], gf[4], uf[4];
#pragma unroll
        for (int i = 0; i < 4; i++)
            af[i] = *(const bf16x8*)&As[(wr * 64 + i * 16 + fr) * BK + fq * 8];
#pragma unroll
        for (int j = 0; j < 4; j++) {
            gf[j] = *(const bf16x8*)&Bgs[(wc * 64 + j * 16 + fr) * BK + fq * 8];
            uf[j] = *(const bf16x8*)&Bus[(wc * 64 + j * 16 + fr) * BK + fq * 8];
        }
#pragma unroll
        for (int i = 0; i < 4; i++)
#pragma unroll
            for (int j = 0; j < 4; j++) {
                accg[i][j] = __builtin_amdgcn_mfma_f32_16x16x32_bf16(af[i], gf[j], accg[i][j], 0, 0, 0);
                accu[i][j] = __builtin_amdgcn_mfma_f32_16x16x32_bf16(af[i], uf[j], accu[i][j], 0, 0, 0);
            }
        __syncthreads();
    }

#pragma unroll
    for (int i = 0; i < 4; i++) {
        int mbase = m0 + wr * 64 + i * 16 + fq * 4;
#pragma unroll
        for (int j = 0; j < 4; j++) {
            int n = n0 + wc * 64 + j * 16 + fr;
#pragma unroll
            for (int rr = 0; rr < 4; rr++) {
                float g = accg[i][j][rr];
                float u = accu[i][j][rr];
                float s = g / (1.f + __expf(-g));
                Cb[(size_t)(mbase + rr) * N + n] = (bf16_t)(s * u);
            }
        }
    }
}

// ---------------- fused RoPE + bf16 convert + relayout of qkv ----------------
// q_bf[b][h][s][d], k_bf[b][kvh][s][d], v_bf[b][kvh][d][s] (transposed)
// grid: (CROWS, NH + 2*NKV), block 128
__global__ __launch_bounds__(128) void qkv_convert_kernel(const float* __restrict__ qkv,
                                                          bf16_t* __restrict__ qb,
                                                          bf16_t* __restrict__ kb,
                                                          bf16_t* __restrict__ vb) {
    int row = blockIdx.x;
    int hh = blockIdx.y;
    int t = threadIdx.x;
    int b = row >> 10, s = row & 1023;
    if (hh < CNH + CNKV) {
        const float* p = qkv + (size_t)row * CQKV +
                         (hh < CNH ? hh * CDH : CQD + (hh - CNH) * CDH);
        int jf = t & 63;
        float inv = __expf(-(float)jf * (13.815510557964274f / 64.0f));  // theta^-jf/64
        float ang = (float)s * inv;
        float c = cosf(ang), si = sinf(ang);
        float x0 = p[t];
        float xo = p[t ^ 64];
        float rot = (t < 64) ? -xo : xo;
        float v = x0 * c + rot * si;
        if (hh < CNH)
            qb[((size_t)(b * CNH + hh) * CS + s) * CDH + t] = (bf16_t)v;
        else
            kb[((size_t)(b * CNKV + (hh - CNH)) * CS + s) * CDH + t] = (bf16_t)v;
    } else {
        int kvh = hh - CNH - CNKV;
        float v = qkv[(size_t)row * CQKV + CQD + CKVD + kvh * CDH + t];
        vb[((size_t)(b * CNKV + kvh) * CDH + t) * CS + s] = (bf16_t)v;
    }
}

// ---------------- flash attention: one block per (b, h, 64-row q-tile) ------------
// 256 thr = 4 waves; wave w owns q rows w*16..w*16+15. bf16 MFMA QK^T and PV.
constexpr int KPAD = 136;  // 128 + 8 bf16 pad (2-way bank aliasing only)
constexpr int VPAD = 68;   // 64 + 4 bf16 pad

__global__ __launch_bounds__(256, 2) void flash_attn_kernel(const bf16_t* __restrict__ qb,
                                                            const bf16_t* __restrict__ kb,
                                                            const bf16_t* __restrict__ vb,
                                                            const int* __restrict__ amask,
                                                            bf16_t* __restrict__ o) {
    int qt = blockIdx.x, h = blockIdx.y, b = blockIdx.z;
    int kvh = h / CGRP;
    int tid = threadIdx.x, wave = tid >> 6, lane = tid & 63;
    int lnm = lane & 15, quad = lane >> 4;
    int bq0 = qt * 64;

    __shared__ __align__(16) bf16_t Ks[64 * KPAD];       // [kk][d]
    __shared__ __align__(16) bf16_t Vs[128 * VPAD];      // [d][s]
    __shared__ __align__(16) bf16_t Ps[4 * 16 * VPAD];   // per-wave P scratch

    const bf16_t* qplane = qb + (size_t)(b * CNH + h) * CS * CDH;
    const bf16_t* kplane = kb + (size_t)(b * CNKV + kvh) * CS * CDH;
    const bf16_t* vplane = vb + (size_t)(b * CNKV + kvh) * CDH * CS;

    // Q fragments (A-layout: m=lane&15, k=quad*8+j), 4 k-steps of 32
    bf16x8 qf[4];
    {
        const bf16_t* qr = qplane + (size_t)(bq0 + wave * 16 + lnm) * CDH + quad * 8;
#pragma unroll
        for (int ks = 0; ks < 4; ks++) qf[ks] = *(const bf16x8*)(qr + ks * 32);
    }

    f32x4 acc_o[8];
#pragma unroll
    for (int f = 0; f < 8; f++) acc_o[f] = {0.f, 0.f, 0.f, 0.f};
    float m_i[4], l_i[4];
#pragma unroll
    for (int rr = 0; rr < 4; rr++) { m_i[rr] = -1e30f; l_i[rr] = 0.f; }

    bf16_t* Pw = &Ps[wave * 16 * VPAD];
    const float scale = 0.08838834764831845f;  // 1/sqrt(128)

    for (int jt = 0; jt <= qt; jt++) {
        int s0 = jt * 64;
        // stage K tile: 64 rows x 128 cols = 1024 chunks of 8; 16 chunks/row
#pragma unroll
        for (int it = 0; it < 4; it++) {
            int idx = tid + it * 256;
            int r = idx >> 4, c = idx & 15;
            *(bf16x8*)&Ks[r * KPAD + c * 8] =
                *(const bf16x8*)(kplane + (size_t)(s0 + r) * CDH + c * 8);
        }
        // stage V tile: 128 rows(d) x 64 cols(s) = 1024 chunks of 8; 8 chunks/row
#pragma unroll
        for (int it = 0; it < 4; it++) {
            int idx = tid + it * 256;
            int r = idx >> 3, c = idx & 7;
            *(bf16x8*)&Vs[r * VPAD + c * 8] =
                *(const bf16x8*)(vplane + (size_t)r * CS + s0 + c * 8);
        }
        __syncthreads();

        // S = Q @ K^T : per wave 16x64
        f32x4 sacc[4];
#pragma unroll
        for (int j = 0; j < 4; j++) sacc[j] = {0.f, 0.f, 0.f, 0.f};
#pragma unroll
        for (int ks = 0; ks < 4; ks++)
#pragma unroll
            for (int j = 0; j < 4; j++) {
                bf16x8 kf = *(const bf16x8*)&Ks[(j * 16 + lnm) * KPAD + ks * 32 + quad * 8];
                sacc[j] = __builtin_amdgcn_mfma_f32_16x16x32_bf16(qf[ks], kf, sacc[j], 0, 0, 0);
            }

        // scale + masks (causal + key padding)
        int qbase = bq0 + wave * 16 + quad * 4;
#pragma unroll
        for (int j = 0; j < 4; j++) {
            int kk = s0 + j * 16 + lnm;
            int am = amask[b * CS + kk];
#pragma unroll
            for (int rr = 0; rr < 4; rr++) {
                float s = sacc[j][rr] * scale;
                if (am == 0 || kk > qbase + rr) s = -1e30f;
                sacc[j][rr] = s;
            }
        }

        // online softmax row stats (row = quad*4+rr; cols spread over lanes&15 x 4 frags)
        float mnew[4], alpha[4], rsum[4];
#pragma unroll
        for (int rr = 0; rr < 4; rr++) {
            float rm = fmaxf(fmaxf(sacc[0][rr], sacc[1][rr]), fmaxf(sacc[2][rr], sacc[3][rr]));
            rm = fmaxf(rm, __shfl_xor(rm, 1));
            rm = fmaxf(rm, __shfl_xor(rm, 2));
            rm = fmaxf(rm, __shfl_xor(rm, 4));
            rm = fmaxf(rm, __shfl_xor(rm, 8));
            float mn = fmaxf(m_i[rr], rm);
            alpha[rr] = __expf(m_i[rr] - mn);
            m_i[rr] = mn;
            mnew[rr] = mn;
            rsum[rr] = 0.f;
        }

        // P = exp(S - m) -> per-wave LDS (C-layout -> A-layout round trip)
#pragma unroll
        for (int j = 0; j < 4; j++)
#pragma unroll
            for (int rr = 0; rr < 4; rr++) {
                float p = __expf(sacc[j][rr] - mnew[rr]);
                rsum[rr] += p;
                Pw[(quad * 4 + rr) * VPAD + j * 16 + lnm] = (bf16_t)p;
            }
#pragma unroll
        for (int rr = 0; rr < 4; rr++) {
            float rs = rsum[rr];
            rs += __shfl_xor(rs, 1);
            rs += __shfl_xor(rs, 2);
            rs += __shfl_xor(rs, 4);
            rs += __shfl_xor(rs, 8);
            l_i[rr] = l_i[rr] * alpha[rr] + rs;
        }
#pragma unroll
        for (int f = 0; f < 8; f++)
#pragma unroll
            for (int rr = 0; rr < 4; rr++) acc_o[f][rr] *= alpha[rr];

        // O += P @ V (k = kv index, 2 k-steps of 32)
#pragma unroll
        for (int ks = 0; ks < 2; ks++) {
            bf16x8 af = *(const bf16x8*)&Pw[lnm * VPAD + ks * 32 + quad * 8];
#pragma unroll
            for (int f = 0; f < 8; f++) {
                bf16x8 vf = *(const bf16x8*)&Vs[(f * 16 + lnm) * VPAD + ks * 32 + quad * 8];
                acc_o[f] = __builtin_amdgcn_mfma_f32_16x16x32_bf16(af, vf, acc_o[f], 0, 0, 0);
            }
        }
        __syncthreads();
    }

    // epilogue: O /= l, write bf16 [b*S+q][h*128+d]
    float inv_l[4];
#pragma unroll
    for (int rr = 0; rr < 4; rr++) inv_l[rr] = 1.f / l_i[rr];
#pragma unroll
    for (int rr = 0; rr < 4; rr++) {
        int orow = bq0 + wave * 16 + quad * 4 + rr;
        bf16_t* op = o + (size_t)(b * CS + orow) * CQD + h * CDH;
#pragma unroll
        for (int f = 0; f < 8; f++)
            op[f * 16 + lnm] = (bf16_t)(acc_o[f][rr] * inv_l[rr]);
    }
}

// ---------------- last_hidden gather ----------------
__global__ __launch_bounds__(256) void last_hidden_kernel(const float* __restrict__ hidden,
                                                          const int* __restrict__ amask,
                                                          float* __restrict__ outlast) {
    int b = blockIdx.x;
    float local = 0.f;
    for (int s = threadIdx.x; s < CS; s += 256) local += (float)amask[b * CS + s];
    local = waveSum(local);
    __shared__ float part[4];
    __shared__ int ssl;
    int wid = threadIdx.x >> 6, lane = threadIdx.x & 63;
    if (lane == 0) part[wid] = local;
    __syncthreads();
    if (threadIdx.x == 0) ssl = (int)(part[0] + part[1] + part[2] + part[3]) - 1;
    __syncthreads();
    int sl = ssl;
    for (int j = threadIdx.x; j < CH; j += 256)
        outlast[(size_t)b * CH + j] = hidden[((size_t)b * CS + sl) * CH + j];
}

extern "C" void kernel_launch(void* const* d_in, const int* in_sizes, int n_in,
                              void* d_out, int out_size, void* d_ws, size_t ws_size,
                              hipStream_t stream) {
    const int* ids = (const int*)d_in[0];
    const int* amask = (const int*)d_in[1];
    const float* emb = (const float*)d_in[2];
    const float* wq = (const float*)d_in[3];
    const float* bq = (const float*)d_in[4];
    const float* wk = (const float*)d_in[5];
    const float* bk = (const float*)d_in[6];
    const float* wv = (const float*)d_in[7];
    const float* bv = (const float*)d_in[8];
    const float* wo = (const float*)d_in[9];
    const float* wg = (const float*)d_in[10];
    const float* wu = (const float*)d_in[11];
    const float* wd = (const float*)d_in[12];
    const float* ln1 = (const float*)d_in[13];
    const float* ln2 = (const float*)d_in[14];
    const float* lnf = (const float*)d_in[15];
    float* out = (float*)d_out;

    // workspace layout (~127.4 MB)
    char* p = (char*)d_ws;
    float* x = (float*)p;      p += (size_t)CROWS * CH * 4;     // 12.6 MB
    float* qkv = (float*)p;    p += (size_t)CROWS * CQKV * 4;   // 16.8 MB
    bf16_t* hb = (bf16_t*)p;   p += (size_t)CROWS * CH * 2;     // 6.3 MB
    bf16_t* act = (bf16_t*)p;  p += (size_t)CROWS * CF * 2;     // 36.7 MB
    bf16_t* wbuf = (bf16_t*)p; p += (size_t)2 * CF * CH * 2;    // 55.1 MB
    float* biasq = (float*)p;  p += (size_t)CL * CQKV * 4;      // 16 KB

    // attention bf16 buffers aliased onto `act` (free until GLU runs)
    bf16_t* q_bf = act;                                     // 2*12*1024*128
    bf16_t* k_bf = q_bf + (size_t)CB * CNH * CS * CDH;      // 2*2*1024*128
    bf16_t* v_bf = k_bf + (size_t)CB * CNKV * CS * CDH;     // 2*2*128*1024

    embed_kernel<<<CROWS, 256, 0, stream>>>(ids, emb, x);
    pack_bias_kernel<<<CL * CQKV / 256, 256, 0, stream>>>(bq, bk, bv, biasq);

    for (int i = 0; i < CL; i++) {
        rmsnorm_kernel<<<CROWS, 256, 0, stream>>>(x, ln1 + (size_t)i * CH, nullptr, hb);

        convT_kernel<<<dim3(CQD / 32, CH / 32), 256, 0, stream>>>(
            wq + (size_t)i * CH * CQD, wbuf, CQD, CH);
        convT_kernel<<<dim3(CKVD / 32, CH / 32), 256, 0, stream>>>(
            wk + (size_t)i * CH * CKVD, wbuf + (size_t)CQD * CH, CKVD, CH);
        convT_kernel<<<dim3(CKVD / 32, CH / 32), 256, 0, stream>>>(
            wv + (size_t)i * CH * CKVD, wbuf + (size_t)(CQD + CKVD) * CH, CKVD, CH);
        gemm_bf16<<<dim3(CQKV / BN, CROWS / BM), 256, 0, stream>>>(
            hb, wbuf, biasq + (size_t)i * CQKV, qkv, CROWS, CQKV, CH, 0);

        qkv_convert_kernel<<<dim3(CROWS, CNH + 2 * CNKV), 128, 0, stream>>>(
            qkv, q_bf, k_bf, v_bf);

        flash_attn_kernel<<<dim3(CS / 64, CNH, CB), 256, 0, stream>>>(
            q_bf, k_bf, v_bf, amask, hb);

        convT_kernel<<<dim3(CH / 32, CQD / 32), 256, 0, stream>>>(
            wo + (size_t)i * CQD * CH, wbuf, CH, CQD);
        gemm_bf16<<<dim3(CH / BN, CROWS / BM), 256, 0, stream>>>(
            hb, wbuf, nullptr, x, CROWS, CH, CQD, 1);

        rmsnorm_kernel<<<CROWS, 256, 0, stream>>>(x, ln2 + (size_t)i * CH, nullptr, hb);

        convT_kernel<<<dim3(CF / 32, CH / 32), 256, 0, stream>>>(
            wg + (size_t)i * CH * CF, wbuf, CF, CH);
        convT_kernel<<<dim3(CF / 32, CH / 32), 256, 0, stream>>>(
            wu + (size_t)i * CH * CF, wbuf + (size_t)CF * CH, CF, CH);
        glu_bf16<<<dim3(CF / BN, CROWS / BM), 256, 0, stream>>>(
            hb, wbuf, wbuf + (size_t)CF * CH, act, CROWS, CF, CH);

        convT_kernel<<<dim3(CH / 32, CF / 32), 256, 0, stream>>>(
            wd + (size_t)i * CF * CH, wbuf, CH, CF);
        gemm_bf16<<<dim3(CH / BN, CROWS / BM), 256, 0, stream>>>(
            act, wbuf, nullptr, x, CROWS, CH, CF, 1);
    }

    rmsnorm_kernel<<<CROWS, 256, 0, stream>>>(x, lnf, out, nullptr);
    last_hidden_kernel<<<CB, 256, 0, stream>>>(out, amask, out + (size_t)CROWS * CH);
}